// Round 2
// baseline (474.108 us; speedup 1.0000x reference)
//
#include <hip/hip_runtime.h>
#include <math.h>

#define B 16
#define N 2000
#define D 25088           // 512*7*7
#define D4 6272           // D/4 (float4 per row)
#define PI2 1.570795f     // 3.14159/2, matches the torch-module constant
#define DCHUNKS 2
#define C4 (D4 / DCHUNKS) // 3136 float4 per d-chunk
#define NCHUNK 20
#define NPER (N / NCHUNK) // 100

__device__ __forceinline__ float wave_sum(float v) {
#pragma unroll
    for (int off = 32; off > 0; off >>= 1) v += __shfl_xor(v, off, 64);
    return v;
}
__device__ __forceinline__ float wave_max(float v) {
#pragma unroll
    for (int off = 32; off > 0; off >>= 1) v = fmaxf(v, __shfl_xor(v, off, 64));
    return v;
}

// ---------------------------------------------------------------------------
// Kernel 1: dots[b][n] = key[b].mem[n] (raw key; normalization cancels in the
// cosine) and mn2[n] = ||mem[n]||^2. Grid (N/4, DCHUNKS): block owns 4 memory
// rows x one d-chunk; float4 loads; partials merged with fp32 HW atomics.
// ---------------------------------------------------------------------------
__global__ __launch_bounds__(256, 3) void k_dots(const float4* __restrict__ key,
                                                 const float4* __restrict__ mem,
                                                 float* __restrict__ dots,
                                                 float* __restrict__ mn2) {
    const int tid = threadIdx.x;
    const int n0  = blockIdx.x * 4;
    const int c0  = blockIdx.y * C4;
    const float4* mrow = mem + (size_t)n0 * D4;

    float acc[4][B];
    float msq[4] = {0.f, 0.f, 0.f, 0.f};
#pragma unroll
    for (int j = 0; j < 4; ++j)
#pragma unroll
        for (int b = 0; b < B; ++b) acc[j][b] = 0.f;

    for (int i = c0 + tid; i < c0 + C4; i += 256) {
        float4 mv[4];
#pragma unroll
        for (int j = 0; j < 4; ++j) mv[j] = mrow[(size_t)j * D4 + i];
#pragma unroll
        for (int j = 0; j < 4; ++j) {
            msq[j] = fmaf(mv[j].x, mv[j].x, msq[j]);
            msq[j] = fmaf(mv[j].y, mv[j].y, msq[j]);
            msq[j] = fmaf(mv[j].z, mv[j].z, msq[j]);
            msq[j] = fmaf(mv[j].w, mv[j].w, msq[j]);
        }
#pragma unroll
        for (int g = 0; g < 4; ++g) {  // b in groups of 4 to bound live kv regs
            float4 kv[4];
#pragma unroll
            for (int t = 0; t < 4; ++t) kv[t] = key[(size_t)(g * 4 + t) * D4 + i];
#pragma unroll
            for (int t = 0; t < 4; ++t) {
                const int b = g * 4 + t;
#pragma unroll
                for (int j = 0; j < 4; ++j) {
                    float a = acc[j][b];
                    a = fmaf(kv[t].x, mv[j].x, a);
                    a = fmaf(kv[t].y, mv[j].y, a);
                    a = fmaf(kv[t].z, mv[j].z, a);
                    a = fmaf(kv[t].w, mv[j].w, a);
                    acc[j][b] = a;
                }
            }
        }
    }

    __shared__ float lds[4][68];
    const int wv = tid >> 6, ln = tid & 63;
#pragma unroll
    for (int j = 0; j < 4; ++j) {
#pragma unroll
        for (int b = 0; b < B; ++b) {
            float v = wave_sum(acc[j][b]);
            if (ln == 0) lds[wv][j * B + b] = v;
        }
        float v = wave_sum(msq[j]);
        if (ln == 0) lds[wv][64 + j] = v;
    }
    __syncthreads();
    if (tid < 68) {
        float v = lds[0][tid] + lds[1][tid] + lds[2][tid] + lds[3][tid];
        if (tid < 64) {
            unsafeAtomicAdd(&dots[(size_t)(tid & 15) * N + n0 + (tid >> 4)], v);
        } else {
            unsafeAtomicAdd(&mn2[n0 + (tid - 64)], v);
        }
    }
}

// ---------------------------------------------------------------------------
// Kernel 2: per-b softmax of tan(cos * PI/2). One block per b. Small.
// ---------------------------------------------------------------------------
__global__ __launch_bounds__(256, 2) void k_softmax(const float4* __restrict__ key,
                                                    const float* __restrict__ dots,
                                                    const float* __restrict__ mn2,
                                                    float* __restrict__ w) {
    const int b = blockIdx.x, tid = threadIdx.x;
    const int wv = tid >> 6, ln = tid & 63;
    __shared__ float t[N];
    __shared__ float redA[4], redB[4], redC[4];

    // ||key_b||^2  (float4 loads)
    float s = 0.f;
    for (int i = tid; i < D4; i += 256) {
        float4 v = key[(size_t)b * D4 + i];
        s = fmaf(v.x, v.x, s);
        s = fmaf(v.y, v.y, s);
        s = fmaf(v.z, v.z, s);
        s = fmaf(v.w, v.w, s);
    }
    s = wave_sum(s);
    if (ln == 0) redA[wv] = s;
    __syncthreads();
    const float kn = fmaxf(sqrtf(redA[0] + redA[1] + redA[2] + redA[3]), 1e-8f);

    // logits + max
    float mx = -1e30f;
    for (int n = tid; n < N; n += 256) {
        float mn  = fmaxf(sqrtf(mn2[n]), 1e-8f);
        float cs  = dots[(size_t)b * N + n] / (kn * mn);
        float tv  = tanf(cs * PI2);
        t[n] = tv;
        mx = fmaxf(mx, tv);
    }
    mx = wave_max(mx);
    if (ln == 0) redB[wv] = mx;
    __syncthreads();
    mx = fmaxf(fmaxf(redB[0], redB[1]), fmaxf(redB[2], redB[3]));

    // exp + sum
    float sum = 0.f;
    for (int n = tid; n < N; n += 256) {
        float e = expf(t[n] - mx);
        t[n] = e;
        sum += e;
    }
    sum = wave_sum(sum);
    if (ln == 0) redC[wv] = sum;
    __syncthreads();
    sum = redC[0] + redC[1] + redC[2] + redC[3];
    const float inv = 1.f / sum;
    for (int n = tid; n < N; n += 256) w[(size_t)b * N + n] = t[n] * inv;
}

// ---------------------------------------------------------------------------
// Kernel 3: out[b][d] = sum_n w[b][n] * mem[n][d]. Grid (25, NCHUNK); w tile
// staged in LDS (broadcast float4 reads); n-loop unrolled x4 -> 4 float4 loads
// in flight per thread; fp32 HW atomics merge the NCHUNK partials.
// ---------------------------------------------------------------------------
__global__ __launch_bounds__(256, 2) void k_out(const float4* __restrict__ mem,
                                                const float* __restrict__ w,
                                                float* __restrict__ out) {
    const int tid = threadIdx.x;
    const int d4  = blockIdx.x * 256 + tid;
    const int n0  = blockIdx.y * NPER;

    __shared__ float wt[B * NPER];
    for (int i = tid; i < B * NPER; i += 256)
        wt[i] = w[(size_t)(i / NPER) * N + n0 + (i % NPER)];
    __syncthreads();
    if (d4 >= D4) return;

    const float4* mp = mem + d4;
    float4 acc[B];
#pragma unroll
    for (int b = 0; b < B; ++b) acc[b] = make_float4(0.f, 0.f, 0.f, 0.f);

    for (int n = 0; n < NPER; n += 4) {
        float4 mv0 = mp[(size_t)(n0 + n + 0) * D4];
        float4 mv1 = mp[(size_t)(n0 + n + 1) * D4];
        float4 mv2 = mp[(size_t)(n0 + n + 2) * D4];
        float4 mv3 = mp[(size_t)(n0 + n + 3) * D4];
#pragma unroll
        for (int b = 0; b < B; ++b) {
            const float4 wv = ((const float4*)wt)[b * (NPER / 4) + (n >> 2)];
            float4 a = acc[b];
            a.x = fmaf(wv.x, mv0.x, a.x); a.y = fmaf(wv.x, mv0.y, a.y);
            a.z = fmaf(wv.x, mv0.z, a.z); a.w = fmaf(wv.x, mv0.w, a.w);
            a.x = fmaf(wv.y, mv1.x, a.x); a.y = fmaf(wv.y, mv1.y, a.y);
            a.z = fmaf(wv.y, mv1.z, a.z); a.w = fmaf(wv.y, mv1.w, a.w);
            a.x = fmaf(wv.z, mv2.x, a.x); a.y = fmaf(wv.z, mv2.y, a.y);
            a.z = fmaf(wv.z, mv2.z, a.z); a.w = fmaf(wv.z, mv2.w, a.w);
            a.x = fmaf(wv.w, mv3.x, a.x); a.y = fmaf(wv.w, mv3.y, a.y);
            a.z = fmaf(wv.w, mv3.z, a.z); a.w = fmaf(wv.w, mv3.w, a.w);
            acc[b] = a;
        }
    }
#pragma unroll
    for (int b = 0; b < B; ++b) {
        float* op = out + (size_t)b * D + (size_t)d4 * 4;
        unsafeAtomicAdd(op + 0, acc[b].x);
        unsafeAtomicAdd(op + 1, acc[b].y);
        unsafeAtomicAdd(op + 2, acc[b].z);
        unsafeAtomicAdd(op + 3, acc[b].w);
    }
}

extern "C" void kernel_launch(void* const* d_in, const int* in_sizes, int n_in,
                              void* d_out, int out_size, void* d_ws, size_t ws_size,
                              hipStream_t stream) {
    const float* key = (const float*)d_in[0];   // [16, 512, 7, 7]
    const float* mem = (const float*)d_in[1];   // [2000, 512, 7, 7]
    float* out = (float*)d_out;                 // [16, 512, 7, 7]

    float* ws   = (float*)d_ws;
    float* dots = ws;                 // B*N = 32000
    float* mn2  = ws + (size_t)B * N; // N   =  2000
    float* w    = mn2 + N;            // B*N = 32000

    hipMemsetAsync(d_out, 0, (size_t)B * D * sizeof(float), stream);
    hipMemsetAsync(ws, 0, (size_t)(B * N + N) * sizeof(float), stream); // dots+mn2
    k_dots<<<dim3(N / 4, DCHUNKS), 256, 0, stream>>>((const float4*)key, (const float4*)mem, dots, mn2);
    k_softmax<<<dim3(B), 256, 0, stream>>>((const float4*)key, dots, mn2, w);
    k_out<<<dim3((D4 + 255) / 256, NCHUNK), 256, 0, stream>>>((const float4*)mem, w, out);
}